// Round 13
// baseline (481.232 us; speedup 1.0000x reference)
//
#include <hip/hip_runtime.h>
#include <math.h>
#include <stdint.h>

// FrequencyAttention: B=8, L=4096, D=1024, H=16, dh=64, F=2049 (pad 2176), k=64
// rfft(X) once (radix-8 Stockham, table twiddles, f16 staged input);
// projections commute with FFT; energy top-k via one fp16 MFMA GEMM over
// interleaved Re/Im rows; sparse attention (MFMA, K-split); sparse irfft as
// MFMA (cos-matrix @ ampT); out GEMM. Big GEMMs: 128x256 block, waves 64x128,
// BK=32, paired-row swizzled LDS (0-conflict), TRIPLE buffer depth-2 prefetch
// (vmcnt(12) steady state), 72KB LDS (2 blocks/CU), XCD remap, no setprio.

typedef _Float16 f16;
typedef _Float16 f16x4 __attribute__((ext_vector_type(4)));
typedef _Float16 f16x8 __attribute__((ext_vector_type(8)));
typedef float f32x4 __attribute__((ext_vector_type(4)));

#define PI_F 3.14159265358979323846f
#define PADJ(j) ((j) + ((j) >> 3))

__device__ __forceinline__ void gl_lds16(const void* g, void* l) {
  __builtin_amdgcn_global_load_lds((const __attribute__((address_space(1))) void*)g,
                                   (__attribute__((address_space(3))) void*)l, 16, 0, 0);
}

__device__ __forceinline__ float2 cadd(float2 a, float2 b) { return make_float2(a.x + b.x, a.y + b.y); }
__device__ __forceinline__ float2 csub(float2 a, float2 b) { return make_float2(a.x - b.x, a.y - b.y); }
__device__ __forceinline__ float2 cmul(float2 a, float2 b) {
  return make_float2(a.x * b.x - a.y * b.y, a.x * b.y + a.y * b.x);
}
__device__ __forceinline__ float2 cmni(float2 a) { return make_float2(a.y, -a.x); }  // a * (-i)

// Paired-row staging: LDS row j (128B) = {global row 2j | 2j+1} of a 64B K-slab,
// slots XOR-permuted by (j&7). NIT = (#global rows)/128 * 2 gl_lds per thread.
template <int NIT>
__device__ __forceinline__ void stgP(const char* g, size_t gstride, int kb, char* lds,
                                     int tid, int w) {
#pragma unroll
  for (int it = 0; it < NIT; ++it) {
    int ls = it * 256 + tid;          // linear 16B slot
    int j = ls >> 3, s = ls & 7;      // LDS row, LDS slot
    int u = s ^ (j & 7);              // unswizzled slot within pair
    int grow = 2 * j + (u >> 2);
    gl_lds16(g + (size_t)grow * gstride + ((u & 3) << 4) + kb, lds + it * 4096 + w * 1024);
  }
}

// byte offset of (global row grow, K-quarter q) in paired-row swizzled LDS
__device__ __forceinline__ int pofs(int grow, int q) {
  int j = grow >> 1;
  int u = ((grow & 1) << 2) | q;
  return j * 128 + ((u ^ (j & 7)) << 4);
}

// ---------- twiddle tables: twtab[j]=W_2048^j, utab[f]=W_4096^f ----------
__global__ __launch_bounds__(256) void k_tw(float2* __restrict__ twtab, float2* __restrict__ utab) {
  int j = blockIdx.x * 256 + threadIdx.x;
  if (j < 2048) {
    float ang = (float)j * (-6.28318530717958647692f / 2048.0f);
    twtab[j] = make_float2(cosf(ang), sinf(ang));
  } else if (j < 4097) {
    int f = j - 2048;
    float ang = (float)f * (-6.28318530717958647692f / 4096.0f);
    utab[f] = make_float2(cosf(ang), sinf(ang));
  }
}

// ---------- prep: transpose Wq, Wo to fp16 [out][in] for MFMA B-operand ----------
__global__ __launch_bounds__(256) void k_prep(const float* __restrict__ Wq, const float* __restrict__ Wo,
                                              f16* __restrict__ WqT, f16* __restrict__ WoT) {
  __shared__ float t[32][33];
  const float* src = blockIdx.z ? Wo : Wq;
  f16* dst = blockIdx.z ? WoT : WqT;
  int c0 = blockIdx.x * 32, r0 = blockIdx.y * 32;
  int tx = threadIdx.x, ty = threadIdx.y;
#pragma unroll
  for (int yy = 0; yy < 4; ++yy)
    t[ty + yy * 8][tx] = src[(size_t)(r0 + ty + yy * 8) * 1024 + c0 + tx];
  __syncthreads();
#pragma unroll
  for (int yy = 0; yy < 4; ++yy)
    dst[(size_t)(c0 + ty + yy * 8) * 1024 + r0 + tx] = (f16)t[tx][ty + yy * 8];
}

// ---------- prep2: transpose Wk, Wv to fp16 (runs after k_fft; lives in region1 tail) ----------
__global__ __launch_bounds__(256) void k_prep2(const float* __restrict__ Wk, const float* __restrict__ Wv,
                                               f16* __restrict__ WkT, f16* __restrict__ WvT) {
  __shared__ float t[32][33];
  const float* src = blockIdx.z ? Wv : Wk;
  f16* dst = blockIdx.z ? WvT : WkT;
  int c0 = blockIdx.x * 32, r0 = blockIdx.y * 32;
  int tx = threadIdx.x, ty = threadIdx.y;
#pragma unroll
  for (int yy = 0; yy < 4; ++yy)
    t[ty + yy * 8][tx] = src[(size_t)(r0 + ty + yy * 8) * 1024 + c0 + tx];
  __syncthreads();
#pragma unroll
  for (int yy = 0; yy < 4; ++yy)
    dst[(size_t)(c0 + ty + yy * 8) * 1024 + r0 + tx] = (f16)t[tx][ty + yy * 8];
}

// ---------- transpose X (B,L,D) f32 -> Xt16 (B,D,L) f16, 64x64 tiles ----------
__global__ __launch_bounds__(256) void k_t1(const float* __restrict__ X, f16* __restrict__ Xt16) {
  __shared__ float t[64][65];
  int b = blockIdx.z;
  int l0 = blockIdx.x * 64, d0 = blockIdx.y * 64;
  int tid = threadIdx.x;
#pragma unroll
  for (int it = 0; it < 16; ++it) {
    int lr = it * 4 + (tid >> 6);
    t[lr][tid & 63] = X[((size_t)b * 4096 + l0 + lr) * 1024 + d0 + (tid & 63)];
  }
  __syncthreads();
#pragma unroll
  for (int it = 0; it < 4; ++it) {
    int dd = it * 16 + (tid >> 4);
    int lc = (tid & 15) * 4;
    f16x4 v;
    v[0] = (f16)t[lc][dd]; v[1] = (f16)t[lc + 1][dd];
    v[2] = (f16)t[lc + 2][dd]; v[3] = (f16)t[lc + 3][dd];
    *(f16x4*)&Xt16[((size_t)b * 1024 + d0 + dd) * 4096 + l0 + lc] = v;
  }
}

// ---------- DFT8 + DIF twiddle + write (Stockham radix-8 stage) ----------
__device__ __forceinline__ void r8_stage(const float2* __restrict__ cur, float2* __restrict__ nxt,
                                         const float2* __restrict__ tw, int tid, int lg) {
  int Ls = 1 << lg;
  int p = tid >> lg, q = tid & (Ls - 1);
  float2 x[8];
#pragma unroll
  for (int u = 0; u < 8; ++u) x[u] = cur[PADJ(tid + 256 * u)];
  float2 s0 = cadd(x[0], x[4]), d0v = csub(x[0], x[4]);
  float2 s1 = cadd(x[2], x[6]), d1v = csub(x[2], x[6]);
  float2 e0 = cadd(s0, s1), e2 = csub(s0, s1);
  float2 md1 = cmni(d1v);
  float2 e1 = cadd(d0v, md1), e3 = csub(d0v, md1);
  float2 t0 = cadd(x[1], x[5]), u0 = csub(x[1], x[5]);
  float2 t1 = cadd(x[3], x[7]), u1 = csub(x[3], x[7]);
  float2 o0 = cadd(t0, t1), o2 = csub(t0, t1);
  float2 mu1 = cmni(u1);
  float2 o1 = cadd(u0, mu1), o3 = csub(u0, mu1);
  const float C8 = 0.70710678118654752440f;
  float2 w1 = make_float2(C8 * (o1.x + o1.y), C8 * (o1.y - o1.x));
  float2 w2 = cmni(o2);
  float2 w3 = make_float2(C8 * (o3.y - o3.x), -C8 * (o3.x + o3.y));
  float2 y[8];
  y[0] = cadd(e0, o0); y[4] = csub(e0, o0);
  y[1] = cadd(e1, w1); y[5] = csub(e1, w1);
  y[2] = cadd(e2, w2); y[6] = csub(e2, w2);
  y[3] = cadd(e3, w3); y[7] = csub(e3, w3);
  int tb = p << lg;
#pragma unroll
  for (int v = 1; v < 8; ++v) y[v] = cmul(y[v], tw[tb * v]);
  int ob = q + (p << (lg + 3));
#pragma unroll
  for (int v = 0; v < 8; ++v) nxt[PADJ(ob + (v << lg))] = y[v];
}

// ---------- rfft(4096 real f16) per (b,dm): 2048-pt radix-8 Stockham + untangle ----------
__global__ __launch_bounds__(256) void k_fft(const f16* __restrict__ Xt16,
                                             const float2* __restrict__ twtab,
                                             const float2* __restrict__ utab,
                                             f16* __restrict__ PReU, f16* __restrict__ PImU,
                                             float* __restrict__ sumXf) {
  __shared__ float2 bufA[2304];
  __shared__ float2 bufB[2304];
  __shared__ float redr[256], redi[256];
  int tid = threadIdx.x;
  int blk = blockIdx.x;

  const f16x8* src = (const f16x8*)(Xt16 + (size_t)blk * 4096);
#pragma unroll
  for (int r = 0; r < 2; ++r) {
    int i8 = r * 256 + tid;  // 8-f16 group -> 4 complex
    f16x8 v = src[i8];
#pragma unroll
    for (int j = 0; j < 4; ++j)
      bufA[PADJ(4 * i8 + j)] = make_float2((float)v[2 * j], (float)v[2 * j + 1]);
  }
  __syncthreads();
  r8_stage(bufA, bufB, twtab, tid, 0);
  __syncthreads();
  r8_stage(bufB, bufA, twtab, tid, 3);
  __syncthreads();
  r8_stage(bufA, bufB, twtab, tid, 6);
  __syncthreads();
#pragma unroll
  for (int h = 0; h < 2; ++h) {
    int i = (h << 8) + tid;
    float2 a0 = bufB[PADJ(i)], a1 = bufB[PADJ(i + 512)];
    float2 a2 = bufB[PADJ(i + 1024)], a3 = bufB[PADJ(i + 1536)];
    float2 s02 = cadd(a0, a2), d02 = csub(a0, a2);
    float2 s13 = cadd(a1, a3), d13m = cmni(csub(a1, a3));
    bufA[PADJ(i)] = cadd(s02, s13);
    bufA[PADJ(i + 512)] = cadd(d02, d13m);
    bufA[PADJ(i + 1024)] = csub(s02, s13);
    bufA[PADJ(i + 1536)] = csub(d02, d13m);
  }
  __syncthreads();
  float sumr = 0.f, sumi = 0.f;
  size_t obase = (size_t)blk * 2049;
  for (int f = tid; f <= 2048; f += 256) {
    int fz = f & 2047, fm = (2048 - f) & 2047;
    float2 z = bufA[PADJ(fz)], m = bufA[PADJ(fm)];
    float Er = 0.5f * (z.x + m.x), Ei = 0.5f * (z.y - m.y);
    float Or = 0.5f * (z.y + m.y), Oi = -0.5f * (z.x - m.x);
    float2 wv = utab[f];
    float Xr = Er + wv.x * Or - wv.y * Oi;
    float Xi = Ei + wv.x * Oi + wv.y * Or;
    PReU[obase + f] = (f16)Xr;
    PImU[obase + f] = (f16)Xi;
    sumr += Xr; sumi += Xi;
  }
  __syncthreads();
  redr[tid] = sumr; redi[tid] = sumi;
  __syncthreads();
  for (int s = 128; s > 0; s >>= 1) {
    if (tid < s) { redr[tid] += redr[tid + s]; redi[tid] += redi[tid + s]; }
    __syncthreads();
  }
  if (tid == 0) { sumXf[2 * blk] = redr[0]; sumXf[2 * blk + 1] = redi[0]; }
}

// ---------- C = mean_f(q_freq) = (sumXf @ Wq + L*bq) / F ----------
__global__ __launch_bounds__(256) void k_C(const float* __restrict__ sumXf, const float* __restrict__ Wq,
                                           const float* __restrict__ bq,
                                           float* __restrict__ Cre, float* __restrict__ Cim) {
  int b = blockIdx.x >> 2;
  int hd = ((blockIdx.x & 3) << 8) + threadIdx.x;
  float accr = 0.f, acci = 0.f;
  for (int dm = 0; dm < 1024; ++dm) {
    float w = Wq[(size_t)dm * 1024 + hd];
    accr += sumXf[2 * (b * 1024 + dm)] * w;
    acci += sumXf[2 * (b * 1024 + dm) + 1] * w;
  }
  Cre[b * 1024 + hd] = (accr + 4096.0f * bq[hd]) * (1.0f / 2049.0f);
  Cim[b * 1024 + hd] = acci * (1.0f / 2049.0f);
}

// ---------- transpose planes (B*D, 2049) -> PT (B, 4352, D) fp16, rows 2f+z ----------
__global__ __launch_bounds__(256) void k_t2(const f16* __restrict__ PReU, const f16* __restrict__ PImU,
                                            f16* __restrict__ PT) {
  __shared__ f16 t[32][33];
  int z = blockIdx.z;
  int b = z >> 1, pl = z & 1;
  const f16* src = pl ? PImU : PReU;
  int f0 = blockIdx.x * 32, d0 = blockIdx.y * 32;
  int tx = threadIdx.x, ty = threadIdx.y;
#pragma unroll
  for (int yy = 0; yy < 4; ++yy) {
    int ff = f0 + tx;
    t[ty + yy * 8][tx] = (ff < 2049) ? src[(size_t)(b * 1024 + d0 + ty + yy * 8) * 2049 + ff] : (f16)0.f;
  }
  __syncthreads();
#pragma unroll
  for (int yy = 0; yy < 4; ++yy)
    PT[((size_t)b * 4352 + 2 * (f0 + ty + yy * 8) + pl) * 1024 + d0 + tx] = t[tx][ty + yy * 8];
}

// ---------- energy GEMM: |PT @ Wq| head-mean; 128x256 block, waves 64x128, BK=32,
// paired-row swizzled LDS, triple-buffer depth-2 prefetch ----------
__global__ __launch_bounds__(256, 2) void k_energy(const f16* __restrict__ PT, const f16* __restrict__ WqT,
                                                   const float* __restrict__ bq, float* __restrict__ energy) {
  __shared__ __align__(16) char sM[3][24576];  // per buffer: A 8KB + B 16KB
  int tid = threadIdx.x;
  int lane = tid & 63, w = tid >> 6;
  int lin = blockIdx.x;                   // 1088 = 136*8
  int sw = (lin & 7) * 136 + (lin >> 3);  // XCD remap
  int bN = sw & 3, Mblk = sw >> 2;        // bN 0..3 (4 heads), Mblk 0..271
  int wr = w >> 1, wc = w & 1;            // wave tile: 64 rows x 128 cols
  f32x4 acc[4][8];
#pragma unroll
  for (int mf = 0; mf < 4; ++mf)
#pragma unroll
    for (int nf = 0; nf < 8; ++nf) acc[mf][nf] = 0;

  const char* gA0 = (const char*)PT + (size_t)(Mblk * 128) * 2048;
  const char* gB0 = (const char*)WqT + (size_t)(bN * 256) * 2048;
  int r = lane & 15, q = lane >> 4;
  int aofs[4], bofs[8];
#pragma unroll
  for (int mf = 0; mf < 4; ++mf) aofs[mf] = pofs(wr * 64 + mf * 16 + r, q);
#pragma unroll
  for (int nf = 0; nf < 8; ++nf) bofs[nf] = 8192 + pofs(wc * 128 + nf * 16 + r, q);

  char* b0 = &sM[0][0];
  char* b1 = &sM[1][0];
  char* b2 = &sM[2][0];
  auto bptr = [&](int i) -> char* { return (i == 0) ? b0 : (i == 1) ? b1 : b2; };
  auto stage = [&](int ks, char* buf) {
    stgP<2>(gA0, 2048, ks * 64, buf, tid, w);
    stgP<4>(gB0, 2048, ks * 64, buf + 8192, tid, w);
  };
  auto compute = [&](const char* base) {
    f16x8 aF[4], bF[8];
#pragma unroll
    for (int mf = 0; mf < 4; ++mf) aF[mf] = *(const f16x8*)(base + aofs[mf]);
#pragma unroll
    for (int nf = 0; nf < 8; ++nf) bF[nf] = *(const f16x8*)(base + bofs[nf]);
#pragma unroll
    for (int mf = 0; mf < 4; ++mf)
#pragma unroll
      for (int nf = 0; nf < 8; ++nf)
        acc[mf][nf] = __builtin_amdgcn_mfma_f32_16x16x32_f16(aF[mf], bF[nf], acc[mf][nf], 0, 0, 0);
  };

  stage(0, b0);
  stage(1, b1);
  int i0 = 0, i2 = 2;
  for (int t = 0; t < 32; ++t) {
    if (t < 30) {
      stage(t + 2, bptr(i2));
      asm volatile("s_waitcnt vmcnt(12)\ns_barrier" ::: "memory");
    } else if (t == 30) {
      asm volatile("s_waitcnt vmcnt(6)\ns_barrier" ::: "memory");
    } else {
      asm volatile("s_waitcnt vmcnt(0)\ns_barrier" ::: "memory");
    }
    compute(bptr(i0));
    asm volatile("s_barrier" ::: "memory");
    i0 = (i0 == 2) ? 0 : i0 + 1;
    i2 = (i2 == 2) ? 0 : i2 + 1;
  }
  // epilogue: rows 4q..4q+3 per quad -> (Re,Im) of two adjacent bins; 2 heads/wave
  int b = Mblk / 34;
  int tIb = Mblk - b * 34;
  int h0 = bN * 4 + wc * 2;
  bool dc0 = (tIb == 0 && wr == 0 && q == 0);
#pragma unroll
  for (int mf = 0; mf < 4; ++mf) {
    float sE0 = 0.f, sO0 = 0.f, sE1 = 0.f, sO1 = 0.f;
#pragma unroll
    for (int nf = 0; nf < 8; ++nf) {
      float re0 = acc[mf][nf][0], im0 = acc[mf][nf][1];
      float re1 = acc[mf][nf][2], im1 = acc[mf][nf][3];
      if (dc0 && mf == 0) re0 += 4096.0f * bq[(h0 + (nf >> 2)) * 64 + (nf & 3) * 16 + r];
      float m0 = sqrtf(re0 * re0 + im0 * im0);
      float m1 = sqrtf(re1 * re1 + im1 * im1);
      if (nf < 4) { sE0 += m0; sO0 += m1; } else { sE1 += m0; sO1 += m1; }
    }
#pragma unroll
    for (int off = 1; off < 16; off <<= 1) {
      sE0 += __shfl_xor(sE0, off);
      sO0 += __shfl_xor(sO0, off);
      sE1 += __shfl_xor(sE1, off);
      sO1 += __shfl_xor(sO1, off);
    }
    if (r == 0) {
      int fp = tIb * 64 + wr * 32 + mf * 8 + (q << 1);
      energy[((size_t)b * 16 + h0) * 2176 + fp] = sE0 * 0.015625f;
      energy[((size_t)b * 16 + h0) * 2176 + fp + 1] = sO0 * 0.015625f;
      energy[((size_t)b * 16 + h0 + 1) * 2176 + fp] = sE1 * 0.015625f;
      energy[((size_t)b * 16 + h0 + 1) * 2176 + fp + 1] = sO1 * 0.015625f;
    }
  }
}

// ---------- top-64 per (b,h), descending, ties -> lower index ----------
__global__ __launch_bounds__(256) void k_topk(const float* __restrict__ energy, int* __restrict__ idxb) {
  __shared__ float vals[2049];
  __shared__ unsigned long long wbest[4];
  int tid = threadIdx.x, bh = blockIdx.x;
  const float* e = energy + (size_t)bh * 2176;
  for (int i = tid; i < 2049; i += 256) vals[i] = e[i];
  __syncthreads();
  for (int it = 0; it < 64; ++it) {
    unsigned long long best = 0ull;
    for (int f = tid; f < 2049; f += 256) {
      unsigned b32 = __float_as_uint(vals[f]);
      b32 = (b32 & 0x80000000u) ? ~b32 : (b32 | 0x80000000u);
      unsigned long long k = ((unsigned long long)b32 << 12) | (unsigned)(4095 - f);
      best = (k > best) ? k : best;
    }
#pragma unroll
    for (int off = 32; off > 0; off >>= 1) {
      unsigned long long o = __shfl_xor(best, off);
      best = (o > best) ? o : best;
    }
    if ((tid & 63) == 0) wbest[tid >> 6] = best;
    __syncthreads();
    if (tid == 0) {
      unsigned long long b0 = wbest[0] > wbest[1] ? wbest[0] : wbest[1];
      unsigned long long b1 = wbest[2] > wbest[3] ? wbest[2] : wbest[3];
      unsigned long long bb = b0 > b1 ? b0 : b1;
      int f = 4095 - (int)(bb & 4095ull);
      idxb[bh * 64 + it] = f;
      vals[f] = -1.0f;
    }
    __syncthreads();
  }
}

// ---------- qkv GEMM: per (b,h), gathered Re rows @ [Wq|Wk|Wv] head slice ----------
__global__ __launch_bounds__(256) void k_qkv(const f16* __restrict__ PT, const int* __restrict__ idxb,
                                             const f16* __restrict__ WqT, const f16* __restrict__ WkT,
                                             const f16* __restrict__ WvT, float* __restrict__ part) {
  __shared__ __align__(16) f16 sA[64 * 64];
  __shared__ __align__(16) f16 sB[192 * 64];
  __shared__ int fjs[64];
  int tid = threadIdx.x, lane = tid & 63, w = tid >> 6;
  int bh = blockIdx.x, ks = blockIdx.y;
  int b = bh >> 4, h = bh & 15;
  if (tid < 64) fjs[tid] = idxb[bh * 64 + tid];
  __syncthreads();
  f32x4 acc[4][3];
#pragma unroll
  for (int mf = 0; mf < 4; ++mf)
#pragma unroll
    for (int nf = 0; nf < 3; ++nf) acc[mf][nf] = 0;

  int l8 = lane & 7;
  int lr = lane >> 3;
  int swz = (l8 ^ lr) << 4;

  for (int kt = 0; kt < 4; ++kt) {
    int kbyte = ks * 512 + kt * 128;
#pragma unroll
    for (int t = 0; t < 2; ++t) {
      int ia = w * 2 + t;
      int row = ia * 8 + lr;
      const char* src = (const char*)PT + (size_t)(b * 4352 + 2 * fjs[row]) * 2048 + kbyte + swz;
      gl_lds16(src, (char*)sA + ia * 1024);
    }
#pragma unroll
    for (int t = 0; t < 6; ++t) {
      int ib = w * 6 + t;
      int row = ib * 8 + lr;
      const f16* Wt = (row < 64) ? WqT : (row < 128) ? WkT : WvT;
      const char* src = (const char*)Wt + (size_t)(h * 64 + (row & 63)) * 2048 + kbyte + swz;
      gl_lds16(src, (char*)sB + ib * 1024);
    }
    __syncthreads();
#pragma unroll
    for (int kk = 0; kk < 64; kk += 32) {
      int cb = (kk << 1) + ((lane >> 4) << 4);
      int r = lane & 15;
      f16x8 aF[4], bF[3];
#pragma unroll
      for (int mf = 0; mf < 4; ++mf) {
        int row = mf * 16 + r;
        aF[mf] = *(const f16x8*)((const char*)sA + row * 128 + (cb ^ ((row & 7) << 4)));
      }
#pragma unroll
      for (int nf = 0; nf < 3; ++nf) {
        int row = w * 48 + nf * 16 + r;
        bF[nf] = *(const f16x8*)((const char*)sB + row * 128 + (cb ^ ((row & 7) << 4)));
      }
#pragma unroll
      for (int mf = 0; mf < 4; ++mf)
#pragma unroll
        for (int nf = 0; nf < 3; ++nf)
          acc[mf][nf] = __builtin_amdgcn_mfma_f32_16x16x32_f16(aF[mf], bF[nf], acc[mf][nf], 0, 0, 0);
    }
    __syncthreads();
  }
  float* pb = part + (size_t)(ks * 128 + bh) * 12288;
#pragma unroll
  for (int mf = 0; mf < 4; ++mf)
#pragma unroll
    for (int nf = 0; nf < 3; ++nf)
#pragma unroll
      for (int rr = 0; rr < 4; ++rr) {
        int m = mf * 16 + ((lane >> 4) << 2) + rr;
        int n = w * 48 + nf * 16 + (lane & 15);
        pb[m * 192 + n] = acc[mf][nf][rr];
      }
}

// ---------- reduce partials, bias at DC bin, scores, softmax, ampT (f16, [d][j]) ----------
__global__ __launch_bounds__(256) void k_attn2(const float* __restrict__ part, const int* __restrict__ idxb,
                                               const float* __restrict__ bq, const float* __restrict__ bk,
                                               const float* __restrict__ bv, const float* __restrict__ Cre,
                                               f16* __restrict__ ampT) {
  __shared__ float sQKV[64][196];
  __shared__ float scores[64], attns[64];
  __shared__ int fjs[64];
  __shared__ int dcrow;
  int tid = threadIdx.x, bh = blockIdx.x;
  int b = bh >> 4, h = bh & 15;
  if (tid == 0) dcrow = -1;
  __syncthreads();
  if (tid < 64) {
    int f = idxb[bh * 64 + tid];
    fjs[tid] = f;
    if (f == 0) dcrow = tid;
  }
  __syncthreads();
  const float4* p0 = (const float4*)(part + (size_t)bh * 12288);
  const size_t s4 = (size_t)128 * 12288 / 4;
#pragma unroll
  for (int it = 0; it < 12; ++it) {
    int e = it * 256 + tid;
    float4 v0 = p0[e], v1 = p0[e + s4], v2 = p0[e + 2 * s4], v3 = p0[e + 3 * s4];
    float4 v;
    v.x = v0.x + v1.x + v2.x + v3.x;
    v.y = v0.y + v1.y + v2.y + v3.y;
    v.z = v0.z + v1.z + v2.z + v3.z;
    v.w = v0.w + v1.w + v2.w + v3.w;
    int m = e / 48, n0 = (e % 48) * 4;
    *(float4*)&sQKV[m][n0] = v;
  }
  __syncthreads();
  if (dcrow >= 0 && tid < 192) {
    const float* bias = (tid < 64) ? bq : (tid < 128) ? bk : bv;
    sQKV[dcrow][tid] += 4096.0f * bias[h * 64 + (tid & 63)];
  }
  __syncthreads();
  {
    int j = tid >> 2, p = tid & 3;
    float s = 0.f;
#pragma unroll
    for (int c = 0; c < 16; ++c) {
      int cc = p * 16 + c;
      s = fmaf(sQKV[j][cc], sQKV[j][64 + cc], s);
    }
    s += __shfl_xor(s, 1);
    s += __shfl_xor(s, 2);
    if (p == 0) scores[j] = s * 0.125f;
  }
  __syncthreads();
  if (tid < 64) {
    float s = scores[tid];
    float m = s;
#pragma unroll
    for (int off = 32; off > 0; off >>= 1) m = fmaxf(m, __shfl_xor(m, off));
    float ev = expf(s - m);
    float sm = ev;
#pragma unroll
    for (int off = 32; off > 0; off >>= 1) sm += __shfl_xor(sm, off);
    attns[tid] = ev / sm;
  }
  __syncthreads();
  {
    int j = tid >> 2, d0 = (tid & 3) * 16;
    float at = attns[j];
    int fj = fjs[j];
    float wj = (fj == 0 || fj == 2048) ? 0.5f : 1.0f;
#pragma unroll
    for (int q4 = 0; q4 < 4; ++q4) {
      float4 c4 = *(const float4*)&Cre[b * 1024 + h * 64 + d0 + q4 * 4];
      float4 vv = *(const float4*)&sQKV[j][128 + d0 + q4 * 4];
      float av0 = wj * (at * vv.x - c4.x);
      float av1 = wj * (at * vv.y - c4.y);
      float av2 = wj * (at * vv.z - c4.z);
      float av3 = wj * (at * vv.w - c4.w);
      f16* o = ampT + (size_t)bh * 4096 + (d0 + q4 * 4) * 64 + j;  // [bh][d][j]
      o[0] = (f16)av0; o[64] = (f16)av1; o[128] = (f16)av2; o[192] = (f16)av3;
    }
  }
}

// ---------- sparse irfft via MFMA: OT[t][d] = (2/L)(cosA[t][j]@ampT[j][d] + g(t)Cim[d]) + [t==0]Cre ----------
__global__ __launch_bounds__(256) void k_ot(const f16* __restrict__ ampT, const int* __restrict__ idxb,
                                            const float* __restrict__ Cre, const float* __restrict__ Cim,
                                            f16* __restrict__ OT) {
  __shared__ __align__(16) f16 sAmp[64][72];
  __shared__ float gbuf[256];
  __shared__ int fjs[64];
  int tid = threadIdx.x, lane = tid & 63, w = tid >> 6;
  int bh = blockIdx.x >> 4, tch = blockIdx.x & 15;
  int b = bh >> 4, h = bh & 15;
  if (tid < 64) fjs[tid] = idxb[bh * 64 + tid];
  {
    int row = tid >> 2, seg = tid & 3;
    const f16* src = ampT + (size_t)bh * 4096 + row * 64 + seg * 16;
    f16x8 v0 = *(const f16x8*)src;
    f16x8 v1 = *(const f16x8*)(src + 8);
    *(f16x8*)&sAmp[row][seg * 16] = v0;
    *(f16x8*)&sAmp[row][seg * 16 + 8] = v1;
  }
  __syncthreads();
  int r = lane & 15, q = lane >> 4;
  int tbase = tch * 256 + w * 64;
  const float cang = 0.00153398078788564123f;  // 2*pi/4096
  f16x8 aF[4][2];
  float ss[4];
#pragma unroll
  for (int mf = 0; mf < 4; ++mf) {
    int t = tbase + mf * 16 + r;
    float s = 0.f;
#pragma unroll
    for (int kk2 = 0; kk2 < 2; ++kk2) {
      f16x8 a;
#pragma unroll
      for (int jj = 0; jj < 8; ++jj) {
        int j = kk2 * 32 + q * 8 + jj;
        int ridx = (fjs[j] * t) & 4095;
        float sn, cs;
        __sincosf((float)ridx * cang, &sn, &cs);
        s += sn;
        a[jj] = (f16)cs;
      }
      aF[mf][kk2] = a;
    }
    ss[mf] = s;
  }
#pragma unroll
  for (int mf = 0; mf < 4; ++mf) {
    ss[mf] += __shfl_xor(ss[mf], 16);
    ss[mf] += __shfl_xor(ss[mf], 32);
  }
  if (q == 0) {
#pragma unroll
    for (int mf = 0; mf < 4; ++mf) {
      int t = tbase + mf * 16 + r;
      float g = ss[mf];
      if (t & 1) {
        int tp = (t <= 2048) ? t : 4096 - t;
        float sg = (t <= 2048) ? 1.f : -1.f;
        float aa = (float)tp * (PI_F / 4096.0f);
        g -= sg * (cosf(aa) / sinf(aa));
      }
      gbuf[w * 64 + mf * 16 + r] = g;
    }
  }
  f16x8 bF[4][2];
#pragma unroll
  for (int nf = 0; nf < 4; ++nf)
#pragma unroll
    for (int kk2 = 0; kk2 < 2; ++kk2)
      bF[nf][kk2] = *(const f16x8*)&sAmp[nf * 16 + r][kk2 * 32 + q * 8];
  f32x4 acc[4][4];
#pragma unroll
  for (int mf = 0; mf < 4; ++mf)
#pragma unroll
    for (int nf = 0; nf < 4; ++nf) acc[mf][nf] = 0;
#pragma unroll
  for (int kk2 = 0; kk2 < 2; ++kk2)
#pragma unroll
    for (int mf = 0; mf < 4; ++mf)
#pragma unroll
      for (int nf = 0; nf < 4; ++nf)
        acc[mf][nf] = __builtin_amdgcn_mfma_f32_16x16x32_f16(aF[mf][kk2], bF[nf][kk2], acc[mf][nf], 0, 0, 0);
  __syncthreads();
  const float s2L = 2.0f / 4096.0f;
#pragma unroll
  for (int nf = 0; nf < 4; ++nf) {
    int d = nf * 16 + r;
    float cim = Cim[b * 1024 + h * 64 + d];
    float cre = Cre[b * 1024 + h * 64 + d];
#pragma unroll
    for (int mf = 0; mf < 4; ++mf) {
#pragma unroll
      for (int rr = 0; rr < 4; ++rr) {
        int ro = mf * 16 + q * 4 + rr;
        int t = tbase + ro;
        float g = gbuf[w * 64 + ro];
        float val = s2L * (acc[mf][nf][rr] + cim * g) + ((t == 0) ? cre : 0.f);
        OT[((size_t)bh * 4096 + t) * 64 + d] = (f16)val;
      }
    }
  }
}

// ---------- final GEMM: out = OT @ Wo + bo; 128x256 block, waves 64x128, BK=32,
// paired-row swizzled LDS, triple-buffer depth-2 prefetch ----------
__global__ __launch_bounds__(256, 2) void k_final(const f16* __restrict__ OT, const f16* __restrict__ WoT,
                                                  const float* __restrict__ bo, float* __restrict__ out) {
  __shared__ __align__(16) char sM[3][24576];
  int tid = threadIdx.x, lane = tid & 63, w = tid >> 6;
  int lin = blockIdx.x;                 // 1024 = 128*8
  int sw = (lin & 7) * 128 + (lin >> 3);
  int bN = sw & 3, Mblk = sw >> 2;      // Mblk 0..255
  int wr = w >> 1, wc = w & 1;
  f32x4 acc[4][8];
#pragma unroll
  for (int mf = 0; mf < 4; ++mf)
#pragma unroll
    for (int nf = 0; nf < 8; ++nf) acc[mf][nf] = 0;
  int b = Mblk >> 5, t0 = (Mblk & 31) * 128;
  const char* gB0 = (const char*)WoT + (size_t)(bN * 256) * 2048;
  int r = lane & 15, q = lane >> 4;
  int aofs[4], bofs[8];
#pragma unroll
  for (int mf = 0; mf < 4; ++mf) aofs[mf] = pofs(wr * 64 + mf * 16 + r, q);
#pragma unroll
  for (int nf = 0; nf < 8; ++nf) bofs[nf] = 8192 + pofs(wc * 128 + nf * 16 + r, q);

  char* b0 = &sM[0][0];
  char* b1 = &sM[1][0];
  char* b2 = &sM[2][0];
  auto bptr = [&](int i) -> char* { return (i == 0) ? b0 : (i == 1) ? b1 : b2; };
  auto stage = [&](int ks, char* buf) {
    const char* gA = (const char*)OT + ((size_t)(b * 16 + (ks >> 1)) * 4096 + t0) * 128;
    stgP<2>(gA, 128, (ks & 1) * 64, buf, tid, w);
    stgP<4>(gB0, 2048, ks * 64, buf + 8192, tid, w);
  };
  auto compute = [&](const char* base) {
    f16x8 aF[4], bF[8];
#pragma unroll
    for (int mf = 0; mf < 4; ++mf) aF[mf] = *(const f16x8*)(base + aofs[mf]);
#pragma unroll
    for (int nf = 0; nf < 8; ++nf) bF[nf] = *(const f16x8*)(base + bofs[nf]);
#pragma unroll
    for (int mf = 0; mf < 4; ++mf)
#pragma unroll
      for (int nf = 0; nf < 8; ++nf)
        acc[mf][nf] = __builtin_amdgcn_mfma_f32_16x16x32_f16(aF[mf], bF[nf], acc[mf][nf], 0, 0, 0);
  };

  stage(0, b0);
  stage(1, b1);
  int i0 = 0, i2 = 2;
  for (int t = 0; t < 32; ++t) {
    if (t < 30) {
      stage(t + 2, bptr(i2));
      asm volatile("s_waitcnt vmcnt(12)\ns_barrier" ::: "memory");
    } else if (t == 30) {
      asm volatile("s_waitcnt vmcnt(6)\ns_barrier" ::: "memory");
    } else {
      asm volatile("s_waitcnt vmcnt(0)\ns_barrier" ::: "memory");
    }
    compute(bptr(i0));
    asm volatile("s_barrier" ::: "memory");
    i0 = (i0 == 2) ? 0 : i0 + 1;
    i2 = (i2 == 2) ? 0 : i2 + 1;
  }
#pragma unroll
  for (int nf = 0; nf < 8; ++nf) {
    int gcol = bN * 256 + wc * 128 + nf * 16 + r;
    float bcol = bo[gcol];
#pragma unroll
    for (int mf = 0; mf < 4; ++mf) {
#pragma unroll
      for (int rr = 0; rr < 4; ++rr) {
        int grow = Mblk * 128 + wr * 64 + mf * 16 + (q << 2) + rr;
        out[(size_t)grow * 1024 + gcol] = acc[mf][nf][rr] + bcol;
      }
    }
  }
}

extern "C" void kernel_launch(void* const* d_in, const int* in_sizes, int n_in,
                              void* d_out, int out_size, void* d_ws, size_t ws_size,
                              hipStream_t stream) {
  const float* X = (const float*)d_in[0];
  const float* Wq = (const float*)d_in[1];
  const float* bq = (const float*)d_in[2];
  const float* Wk = (const float*)d_in[3];
  const float* bk = (const float*)d_in[4];
  const float* Wv = (const float*)d_in[5];
  const float* bv = (const float*)d_in[6];
  const float* Wo = (const float*)d_in[7];
  const float* bo = (const float*)d_in[8];
  float* out = (float*)d_out;

  if (ws_size < 208928768ULL) return;
  char* w = (char*)d_ws;
  // Region1 (0..134MB): Xt16 f16 (B,D,L) 67MB; after FFT reused for PT (71MB);
  // [71.3M) WkT WvT part (written after k_fft only)
  f16* Xt16 = (f16*)(w);
  f16* PT = (f16*)(w);
  f16* WkT = (f16*)(w + 71303168);
  f16* WvT = (f16*)(w + 73400320);
  float* part = (float*)(w + 75497472);
  char* R2 = w + 134217728;
  f16* PReU = (f16*)(R2);
  f16* PImU = (f16*)(R2 + 33570816);
  f16* OT = (f16*)(R2);
  char* R3 = R2 + 67141632;
  float* sumXf = (float*)(R3);
  float* Cre = (float*)(R3 + 65536);
  float* Cim = (float*)(R3 + 98304);
  float* energy = (float*)(R3 + 131072);
  int* idxb = (int*)(R3 + 1245184);
  f16* ampT = (f16*)(R3 + 1277952);
  f16* WqT = (f16*)(R3 + 3375104);
  f16* WoT = (f16*)(R3 + 5472256);
  // FFT tables live in d_out's head: dead until k_final overwrites all of d_out.
  float2* twtab = (float2*)d_out;
  float2* utab = twtab + 2048;

  dim3 b32(32, 8);
  hipLaunchKernelGGL(k_tw, dim3(17), dim3(256), 0, stream, twtab, utab);
  hipLaunchKernelGGL(k_prep, dim3(32, 32, 2), b32, 0, stream, Wq, Wo, WqT, WoT);
  hipLaunchKernelGGL(k_t1, dim3(64, 16, 8), dim3(256), 0, stream, X, Xt16);
  hipLaunchKernelGGL(k_fft, dim3(8192), dim3(256), 0, stream, Xt16, twtab, utab, PReU, PImU, sumXf);
  hipLaunchKernelGGL(k_prep2, dim3(32, 32, 2), b32, 0, stream, Wk, Wv, WkT, WvT);
  hipLaunchKernelGGL(k_C, dim3(32), dim3(256), 0, stream, sumXf, Wq, bq, Cre, Cim);
  hipLaunchKernelGGL(k_t2, dim3(68, 32, 16), b32, 0, stream, PReU, PImU, PT);
  hipLaunchKernelGGL(k_energy, dim3(1088), dim3(256), 0, stream, PT, WqT, bq, energy);
  hipLaunchKernelGGL(k_topk, dim3(128), dim3(256), 0, stream, energy, idxb);
  hipLaunchKernelGGL(k_qkv, dim3(128, 4), dim3(256), 0, stream, PT, idxb, WqT, WkT, WvT, part);
  hipLaunchKernelGGL(k_attn2, dim3(128), dim3(256), 0, stream, part, idxb, bq, bk, bv, Cre, ampT);
  hipLaunchKernelGGL(k_ot, dim3(2048), dim3(256), 0, stream, ampT, idxb, Cre, Cim, OT);
  hipLaunchKernelGGL(k_final, dim3(1024), dim3(256), 0, stream, OT, WoT, bo, out);
}

// Round 14
// 473.375 us; speedup vs baseline: 1.0166x; 1.0166x over previous
//
#include <hip/hip_runtime.h>
#include <math.h>
#include <stdint.h>

// FrequencyAttention: B=8, L=4096, D=1024, H=16, dh=64, F=2049 (pad 2176), k=64
// rfft(X) once (radix-8 Stockham, table twiddles, f16 staged input);
// projections commute with FFT; energy top-k via one fp16 MFMA GEMM over
// interleaved Re/Im rows; sparse attention (MFMA, K-split); sparse irfft as
// MFMA (cos-matrix @ ampT); out GEMM. Big GEMMs: 128x256 block, waves 64x128,
// BK=32, paired-row swizzled LDS (0-conflict), depth-1 double buffer
// (measured-best R11 config: 91us), vmcnt(6), no setprio, 2 blocks/CU.

typedef _Float16 f16;
typedef _Float16 f16x4 __attribute__((ext_vector_type(4)));
typedef _Float16 f16x8 __attribute__((ext_vector_type(8)));
typedef float f32x4 __attribute__((ext_vector_type(4)));

#define PI_F 3.14159265358979323846f
#define PADJ(j) ((j) + ((j) >> 3))

__device__ __forceinline__ void gl_lds16(const void* g, void* l) {
  __builtin_amdgcn_global_load_lds((const __attribute__((address_space(1))) void*)g,
                                   (__attribute__((address_space(3))) void*)l, 16, 0, 0);
}

__device__ __forceinline__ float2 cadd(float2 a, float2 b) { return make_float2(a.x + b.x, a.y + b.y); }
__device__ __forceinline__ float2 csub(float2 a, float2 b) { return make_float2(a.x - b.x, a.y - b.y); }
__device__ __forceinline__ float2 cmul(float2 a, float2 b) {
  return make_float2(a.x * b.x - a.y * b.y, a.x * b.y + a.y * b.x);
}
__device__ __forceinline__ float2 cmni(float2 a) { return make_float2(a.y, -a.x); }  // a * (-i)

// Paired-row staging: LDS row j (128B) = {global row 2j | 2j+1} of a 64B K-slab,
// slots XOR-permuted by (j&7). NIT = (#global rows)/128 * 2 gl_lds per thread.
template <int NIT>
__device__ __forceinline__ void stgP(const char* g, size_t gstride, int kb, char* lds,
                                     int tid, int w) {
#pragma unroll
  for (int it = 0; it < NIT; ++it) {
    int ls = it * 256 + tid;          // linear 16B slot
    int j = ls >> 3, s = ls & 7;      // LDS row, LDS slot
    int u = s ^ (j & 7);              // unswizzled slot within pair
    int grow = 2 * j + (u >> 2);
    gl_lds16(g + (size_t)grow * gstride + ((u & 3) << 4) + kb, lds + it * 4096 + w * 1024);
  }
}

// byte offset of (global row grow, K-quarter q) in paired-row swizzled LDS
__device__ __forceinline__ int pofs(int grow, int q) {
  int j = grow >> 1;
  int u = ((grow & 1) << 2) | q;
  return j * 128 + ((u ^ (j & 7)) << 4);
}

// ---------- twiddle tables: twtab[j]=W_2048^j, utab[f]=W_4096^f ----------
__global__ __launch_bounds__(256) void k_tw(float2* __restrict__ twtab, float2* __restrict__ utab) {
  int j = blockIdx.x * 256 + threadIdx.x;
  if (j < 2048) {
    float ang = (float)j * (-6.28318530717958647692f / 2048.0f);
    twtab[j] = make_float2(cosf(ang), sinf(ang));
  } else if (j < 4097) {
    int f = j - 2048;
    float ang = (float)f * (-6.28318530717958647692f / 4096.0f);
    utab[f] = make_float2(cosf(ang), sinf(ang));
  }
}

// ---------- prep: transpose Wq, Wo to fp16 [out][in] for MFMA B-operand ----------
__global__ __launch_bounds__(256) void k_prep(const float* __restrict__ Wq, const float* __restrict__ Wo,
                                              f16* __restrict__ WqT, f16* __restrict__ WoT) {
  __shared__ float t[32][33];
  const float* src = blockIdx.z ? Wo : Wq;
  f16* dst = blockIdx.z ? WoT : WqT;
  int c0 = blockIdx.x * 32, r0 = blockIdx.y * 32;
  int tx = threadIdx.x, ty = threadIdx.y;
#pragma unroll
  for (int yy = 0; yy < 4; ++yy)
    t[ty + yy * 8][tx] = src[(size_t)(r0 + ty + yy * 8) * 1024 + c0 + tx];
  __syncthreads();
#pragma unroll
  for (int yy = 0; yy < 4; ++yy)
    dst[(size_t)(c0 + ty + yy * 8) * 1024 + r0 + tx] = (f16)t[tx][ty + yy * 8];
}

// ---------- prep2: transpose Wk, Wv to fp16 (runs after k_fft; lives in region1 tail) ----------
__global__ __launch_bounds__(256) void k_prep2(const float* __restrict__ Wk, const float* __restrict__ Wv,
                                               f16* __restrict__ WkT, f16* __restrict__ WvT) {
  __shared__ float t[32][33];
  const float* src = blockIdx.z ? Wv : Wk;
  f16* dst = blockIdx.z ? WvT : WkT;
  int c0 = blockIdx.x * 32, r0 = blockIdx.y * 32;
  int tx = threadIdx.x, ty = threadIdx.y;
#pragma unroll
  for (int yy = 0; yy < 4; ++yy)
    t[ty + yy * 8][tx] = src[(size_t)(r0 + ty + yy * 8) * 1024 + c0 + tx];
  __syncthreads();
#pragma unroll
  for (int yy = 0; yy < 4; ++yy)
    dst[(size_t)(c0 + ty + yy * 8) * 1024 + r0 + tx] = (f16)t[tx][ty + yy * 8];
}

// ---------- transpose X (B,L,D) f32 -> Xt16 (B,D,L) f16, 64x64 tiles ----------
__global__ __launch_bounds__(256) void k_t1(const float* __restrict__ X, f16* __restrict__ Xt16) {
  __shared__ float t[64][65];
  int b = blockIdx.z;
  int l0 = blockIdx.x * 64, d0 = blockIdx.y * 64;
  int tid = threadIdx.x;
#pragma unroll
  for (int it = 0; it < 16; ++it) {
    int lr = it * 4 + (tid >> 6);
    t[lr][tid & 63] = X[((size_t)b * 4096 + l0 + lr) * 1024 + d0 + (tid & 63)];
  }
  __syncthreads();
#pragma unroll
  for (int it = 0; it < 4; ++it) {
    int dd = it * 16 + (tid >> 4);
    int lc = (tid & 15) * 4;
    f16x4 v;
    v[0] = (f16)t[lc][dd]; v[1] = (f16)t[lc + 1][dd];
    v[2] = (f16)t[lc + 2][dd]; v[3] = (f16)t[lc + 3][dd];
    *(f16x4*)&Xt16[((size_t)b * 1024 + d0 + dd) * 4096 + l0 + lc] = v;
  }
}

// ---------- DFT8 + DIF twiddle + write (Stockham radix-8 stage) ----------
__device__ __forceinline__ void r8_stage(const float2* __restrict__ cur, float2* __restrict__ nxt,
                                         const float2* __restrict__ tw, int tid, int lg) {
  int Ls = 1 << lg;
  int p = tid >> lg, q = tid & (Ls - 1);
  float2 x[8];
#pragma unroll
  for (int u = 0; u < 8; ++u) x[u] = cur[PADJ(tid + 256 * u)];
  float2 s0 = cadd(x[0], x[4]), d0v = csub(x[0], x[4]);
  float2 s1 = cadd(x[2], x[6]), d1v = csub(x[2], x[6]);
  float2 e0 = cadd(s0, s1), e2 = csub(s0, s1);
  float2 md1 = cmni(d1v);
  float2 e1 = cadd(d0v, md1), e3 = csub(d0v, md1);
  float2 t0 = cadd(x[1], x[5]), u0 = csub(x[1], x[5]);
  float2 t1 = cadd(x[3], x[7]), u1 = csub(x[3], x[7]);
  float2 o0 = cadd(t0, t1), o2 = csub(t0, t1);
  float2 mu1 = cmni(u1);
  float2 o1 = cadd(u0, mu1), o3 = csub(u0, mu1);
  const float C8 = 0.70710678118654752440f;
  float2 w1 = make_float2(C8 * (o1.x + o1.y), C8 * (o1.y - o1.x));
  float2 w2 = cmni(o2);
  float2 w3 = make_float2(C8 * (o3.y - o3.x), -C8 * (o3.x + o3.y));
  float2 y[8];
  y[0] = cadd(e0, o0); y[4] = csub(e0, o0);
  y[1] = cadd(e1, w1); y[5] = csub(e1, w1);
  y[2] = cadd(e2, w2); y[6] = csub(e2, w2);
  y[3] = cadd(e3, w3); y[7] = csub(e3, w3);
  int tb = p << lg;
#pragma unroll
  for (int v = 1; v < 8; ++v) y[v] = cmul(y[v], tw[tb * v]);
  int ob = q + (p << (lg + 3));
#pragma unroll
  for (int v = 0; v < 8; ++v) nxt[PADJ(ob + (v << lg))] = y[v];
}

// ---------- rfft(4096 real f16) per (b,dm): 2048-pt radix-8 Stockham + untangle ----------
__global__ __launch_bounds__(256) void k_fft(const f16* __restrict__ Xt16,
                                             const float2* __restrict__ twtab,
                                             const float2* __restrict__ utab,
                                             f16* __restrict__ PReU, f16* __restrict__ PImU,
                                             float* __restrict__ sumXf) {
  __shared__ float2 bufA[2304];
  __shared__ float2 bufB[2304];
  __shared__ float redr[256], redi[256];
  int tid = threadIdx.x;
  int blk = blockIdx.x;

  const f16x8* src = (const f16x8*)(Xt16 + (size_t)blk * 4096);
#pragma unroll
  for (int r = 0; r < 2; ++r) {
    int i8 = r * 256 + tid;  // 8-f16 group -> 4 complex
    f16x8 v = src[i8];
#pragma unroll
    for (int j = 0; j < 4; ++j)
      bufA[PADJ(4 * i8 + j)] = make_float2((float)v[2 * j], (float)v[2 * j + 1]);
  }
  __syncthreads();
  r8_stage(bufA, bufB, twtab, tid, 0);
  __syncthreads();
  r8_stage(bufB, bufA, twtab, tid, 3);
  __syncthreads();
  r8_stage(bufA, bufB, twtab, tid, 6);
  __syncthreads();
#pragma unroll
  for (int h = 0; h < 2; ++h) {
    int i = (h << 8) + tid;
    float2 a0 = bufB[PADJ(i)], a1 = bufB[PADJ(i + 512)];
    float2 a2 = bufB[PADJ(i + 1024)], a3 = bufB[PADJ(i + 1536)];
    float2 s02 = cadd(a0, a2), d02 = csub(a0, a2);
    float2 s13 = cadd(a1, a3), d13m = cmni(csub(a1, a3));
    bufA[PADJ(i)] = cadd(s02, s13);
    bufA[PADJ(i + 512)] = cadd(d02, d13m);
    bufA[PADJ(i + 1024)] = csub(s02, s13);
    bufA[PADJ(i + 1536)] = csub(d02, d13m);
  }
  __syncthreads();
  float sumr = 0.f, sumi = 0.f;
  size_t obase = (size_t)blk * 2049;
  for (int f = tid; f <= 2048; f += 256) {
    int fz = f & 2047, fm = (2048 - f) & 2047;
    float2 z = bufA[PADJ(fz)], m = bufA[PADJ(fm)];
    float Er = 0.5f * (z.x + m.x), Ei = 0.5f * (z.y - m.y);
    float Or = 0.5f * (z.y + m.y), Oi = -0.5f * (z.x - m.x);
    float2 wv = utab[f];
    float Xr = Er + wv.x * Or - wv.y * Oi;
    float Xi = Ei + wv.x * Oi + wv.y * Or;
    PReU[obase + f] = (f16)Xr;
    PImU[obase + f] = (f16)Xi;
    sumr += Xr; sumi += Xi;
  }
  __syncthreads();
  redr[tid] = sumr; redi[tid] = sumi;
  __syncthreads();
  for (int s = 128; s > 0; s >>= 1) {
    if (tid < s) { redr[tid] += redr[tid + s]; redi[tid] += redi[tid + s]; }
    __syncthreads();
  }
  if (tid == 0) { sumXf[2 * blk] = redr[0]; sumXf[2 * blk + 1] = redi[0]; }
}

// ---------- C = mean_f(q_freq) = (sumXf @ Wq + L*bq) / F ----------
__global__ __launch_bounds__(256) void k_C(const float* __restrict__ sumXf, const float* __restrict__ Wq,
                                           const float* __restrict__ bq,
                                           float* __restrict__ Cre, float* __restrict__ Cim) {
  int b = blockIdx.x >> 2;
  int hd = ((blockIdx.x & 3) << 8) + threadIdx.x;
  float accr = 0.f, acci = 0.f;
  for (int dm = 0; dm < 1024; ++dm) {
    float w = Wq[(size_t)dm * 1024 + hd];
    accr += sumXf[2 * (b * 1024 + dm)] * w;
    acci += sumXf[2 * (b * 1024 + dm) + 1] * w;
  }
  Cre[b * 1024 + hd] = (accr + 4096.0f * bq[hd]) * (1.0f / 2049.0f);
  Cim[b * 1024 + hd] = acci * (1.0f / 2049.0f);
}

// ---------- transpose planes (B*D, 2049) -> PT (B, 4352, D) fp16, rows 2f+z ----------
// 32(f) x 64(dm) tiles; scalar coalesced reads, f16x4 vectorized writes.
__global__ __launch_bounds__(256) void k_t2(const f16* __restrict__ PReU, const f16* __restrict__ PImU,
                                            f16* __restrict__ PT) {
  __shared__ f16 t[32][66];  // [f][dm], 33-dword rows -> conflict-free
  int z = blockIdx.z;
  int b = z >> 1, pl = z & 1;
  const f16* src = pl ? PImU : PReU;
  int f0 = blockIdx.x * 32, d0 = blockIdx.y * 64;
  int tid = threadIdx.x;
#pragma unroll
  for (int p = 0; p < 8; ++p) {
    int dm = p * 8 + (tid >> 5);
    int ff = f0 + (tid & 31);
    t[tid & 31][dm] = (ff < 2049) ? src[(size_t)(b * 1024 + d0 + dm) * 2049 + ff] : (f16)0.f;
  }
  __syncthreads();
#pragma unroll
  for (int p = 0; p < 2; ++p) {
    int fr = p * 16 + (tid >> 4);
    int dm = (tid & 15) * 4;
    f16x4 v;
    v[0] = t[fr][dm]; v[1] = t[fr][dm + 1]; v[2] = t[fr][dm + 2]; v[3] = t[fr][dm + 3];
    *(f16x4*)&PT[((size_t)b * 4352 + 2 * (f0 + fr) + pl) * 1024 + d0 + dm] = v;
  }
}

// ---------- energy GEMM: |PT @ Wq| head-mean; 128x256 block, waves 64x128, BK=32,
// paired-row swizzled LDS, depth-1 double buffer (measured-best) ----------
__global__ __launch_bounds__(256, 2) void k_energy(const f16* __restrict__ PT, const f16* __restrict__ WqT,
                                                   const float* __restrict__ bq, float* __restrict__ energy) {
  __shared__ __align__(16) char sM[2][24576];  // per buffer: A 8KB + B 16KB
  int tid = threadIdx.x;
  int lane = tid & 63, w = tid >> 6;
  int lin = blockIdx.x;                   // 1088 = 136*8
  int sw = (lin & 7) * 136 + (lin >> 3);  // XCD remap
  int bN = sw & 3, Mblk = sw >> 2;        // bN 0..3 (4 heads), Mblk 0..271
  int wr = w >> 1, wc = w & 1;            // wave tile: 64 rows x 128 cols
  f32x4 acc[4][8];
#pragma unroll
  for (int mf = 0; mf < 4; ++mf)
#pragma unroll
    for (int nf = 0; nf < 8; ++nf) acc[mf][nf] = 0;

  const char* gA0 = (const char*)PT + (size_t)(Mblk * 128) * 2048;
  const char* gB0 = (const char*)WqT + (size_t)(bN * 256) * 2048;
  int r = lane & 15, q = lane >> 4;
  int aofs[4], bofs[8];
#pragma unroll
  for (int mf = 0; mf < 4; ++mf) aofs[mf] = pofs(wr * 64 + mf * 16 + r, q);
#pragma unroll
  for (int nf = 0; nf < 8; ++nf) bofs[nf] = 8192 + pofs(wc * 128 + nf * 16 + r, q);

  char* b0 = &sM[0][0];
  char* b1 = &sM[1][0];
  auto compute = [&](const char* base) {
    f16x8 aF[4], bF[8];
#pragma unroll
    for (int mf = 0; mf < 4; ++mf) aF[mf] = *(const f16x8*)(base + aofs[mf]);
#pragma unroll
    for (int nf = 0; nf < 8; ++nf) bF[nf] = *(const f16x8*)(base + bofs[nf]);
#pragma unroll
    for (int mf = 0; mf < 4; ++mf)
#pragma unroll
      for (int nf = 0; nf < 8; ++nf)
        acc[mf][nf] = __builtin_amdgcn_mfma_f32_16x16x32_f16(aF[mf], bF[nf], acc[mf][nf], 0, 0, 0);
  };

  stgP<2>(gA0, 2048, 0, b0, tid, w);
  stgP<4>(gB0, 2048, 0, b0 + 8192, tid, w);
  for (int t = 0; t < 16; ++t) {
    int kb1 = (2 * t + 1) * 64;
    stgP<2>(gA0, 2048, kb1, b1, tid, w);
    stgP<4>(gB0, 2048, kb1, b1 + 8192, tid, w);
    asm volatile("s_waitcnt vmcnt(6)\ns_barrier" ::: "memory");
    compute(b0);
    asm volatile("s_barrier" ::: "memory");
    if (t < 15) {
      int kb0 = (2 * t + 2) * 64;
      stgP<2>(gA0, 2048, kb0, b0, tid, w);
      stgP<4>(gB0, 2048, kb0, b0 + 8192, tid, w);
      asm volatile("s_waitcnt vmcnt(6)\ns_barrier" ::: "memory");
    } else {
      asm volatile("s_waitcnt vmcnt(0)\ns_barrier" ::: "memory");
    }
    compute(b1);
    asm volatile("s_barrier" ::: "memory");
  }
  // epilogue: rows 4q..4q+3 per quad -> (Re,Im) of two adjacent bins; 2 heads/wave
  int b = Mblk / 34;
  int tIb = Mblk - b * 34;
  int h0 = bN * 4 + wc * 2;
  bool dc0 = (tIb == 0 && wr == 0 && q == 0);
#pragma unroll
  for (int mf = 0; mf < 4; ++mf) {
    float sE0 = 0.f, sO0 = 0.f, sE1 = 0.f, sO1 = 0.f;
#pragma unroll
    for (int nf = 0; nf < 8; ++nf) {
      float re0 = acc[mf][nf][0], im0 = acc[mf][nf][1];
      float re1 = acc[mf][nf][2], im1 = acc[mf][nf][3];
      if (dc0 && mf == 0) re0 += 4096.0f * bq[(h0 + (nf >> 2)) * 64 + (nf & 3) * 16 + r];
      float m0 = sqrtf(re0 * re0 + im0 * im0);
      float m1 = sqrtf(re1 * re1 + im1 * im1);
      if (nf < 4) { sE0 += m0; sO0 += m1; } else { sE1 += m0; sO1 += m1; }
    }
#pragma unroll
    for (int off = 1; off < 16; off <<= 1) {
      sE0 += __shfl_xor(sE0, off);
      sO0 += __shfl_xor(sO0, off);
      sE1 += __shfl_xor(sE1, off);
      sO1 += __shfl_xor(sO1, off);
    }
    if (r == 0) {
      int fp = tIb * 64 + wr * 32 + mf * 8 + (q << 1);
      energy[((size_t)b * 16 + h0) * 2176 + fp] = sE0 * 0.015625f;
      energy[((size_t)b * 16 + h0) * 2176 + fp + 1] = sO0 * 0.015625f;
      energy[((size_t)b * 16 + h0 + 1) * 2176 + fp] = sE1 * 0.015625f;
      energy[((size_t)b * 16 + h0 + 1) * 2176 + fp + 1] = sO1 * 0.015625f;
    }
  }
}

// ---------- top-64 per (b,h), descending, ties -> lower index ----------
__global__ __launch_bounds__(256) void k_topk(const float* __restrict__ energy, int* __restrict__ idxb) {
  __shared__ float vals[2049];
  __shared__ unsigned long long wbest[4];
  int tid = threadIdx.x, bh = blockIdx.x;
  const float* e = energy + (size_t)bh * 2176;
  for (int i = tid; i < 2049; i += 256) vals[i] = e[i];
  __syncthreads();
  for (int it = 0; it < 64; ++it) {
    unsigned long long best = 0ull;
    for (int f = tid; f < 2049; f += 256) {
      unsigned b32 = __float_as_uint(vals[f]);
      b32 = (b32 & 0x80000000u) ? ~b32 : (b32 | 0x80000000u);
      unsigned long long k = ((unsigned long long)b32 << 12) | (unsigned)(4095 - f);
      best = (k > best) ? k : best;
    }
#pragma unroll
    for (int off = 32; off > 0; off >>= 1) {
      unsigned long long o = __shfl_xor(best, off);
      best = (o > best) ? o : best;
    }
    if ((tid & 63) == 0) wbest[tid >> 6] = best;
    __syncthreads();
    if (tid == 0) {
      unsigned long long b0 = wbest[0] > wbest[1] ? wbest[0] : wbest[1];
      unsigned long long b1 = wbest[2] > wbest[3] ? wbest[2] : wbest[3];
      unsigned long long bb = b0 > b1 ? b0 : b1;
      int f = 4095 - (int)(bb & 4095ull);
      idxb[bh * 64 + it] = f;
      vals[f] = -1.0f;
    }
    __syncthreads();
  }
}

// ---------- qkv GEMM: per (b,h), gathered Re rows @ [Wq|Wk|Wv] head slice ----------
__global__ __launch_bounds__(256) void k_qkv(const f16* __restrict__ PT, const int* __restrict__ idxb,
                                             const f16* __restrict__ WqT, const f16* __restrict__ WkT,
                                             const f16* __restrict__ WvT, float* __restrict__ part) {
  __shared__ __align__(16) f16 sA[64 * 64];
  __shared__ __align__(16) f16 sB[192 * 64];
  __shared__ int fjs[64];
  int tid = threadIdx.x, lane = tid & 63, w = tid >> 6;
  int bh = blockIdx.x, ks = blockIdx.y;
  int b = bh >> 4, h = bh & 15;
  if (tid < 64) fjs[tid] = idxb[bh * 64 + tid];
  __syncthreads();
  f32x4 acc[4][3];
#pragma unroll
  for (int mf = 0; mf < 4; ++mf)
#pragma unroll
    for (int nf = 0; nf < 3; ++nf) acc[mf][nf] = 0;

  int l8 = lane & 7;
  int lr = lane >> 3;
  int swz = (l8 ^ lr) << 4;

  for (int kt = 0; kt < 4; ++kt) {
    int kbyte = ks * 512 + kt * 128;
#pragma unroll
    for (int t = 0; t < 2; ++t) {
      int ia = w * 2 + t;
      int row = ia * 8 + lr;
      const char* src = (const char*)PT + (size_t)(b * 4352 + 2 * fjs[row]) * 2048 + kbyte + swz;
      gl_lds16(src, (char*)sA + ia * 1024);
    }
#pragma unroll
    for (int t = 0; t < 6; ++t) {
      int ib = w * 6 + t;
      int row = ib * 8 + lr;
      const f16* Wt = (row < 64) ? WqT : (row < 128) ? WkT : WvT;
      const char* src = (const char*)Wt + (size_t)(h * 64 + (row & 63)) * 2048 + kbyte + swz;
      gl_lds16(src, (char*)sB + ib * 1024);
    }
    __syncthreads();
#pragma unroll
    for (int kk = 0; kk < 64; kk += 32) {
      int cb = (kk << 1) + ((lane >> 4) << 4);
      int r = lane & 15;
      f16x8 aF[4], bF[3];
#pragma unroll
      for (int mf = 0; mf < 4; ++mf) {
        int row = mf * 16 + r;
        aF[mf] = *(const f16x8*)((const char*)sA + row * 128 + (cb ^ ((row & 7) << 4)));
      }
#pragma unroll
      for (int nf = 0; nf < 3; ++nf) {
        int row = w * 48 + nf * 16 + r;
        bF[nf] = *(const f16x8*)((const char*)sB + row * 128 + (cb ^ ((row & 7) << 4)));
      }
#pragma unroll
      for (int mf = 0; mf < 4; ++mf)
#pragma unroll
        for (int nf = 0; nf < 3; ++nf)
          acc[mf][nf] = __builtin_amdgcn_mfma_f32_16x16x32_f16(aF[mf], bF[nf], acc[mf][nf], 0, 0, 0);
    }
    __syncthreads();
  }
  float* pb = part + (size_t)(ks * 128 + bh) * 12288;
#pragma unroll
  for (int mf = 0; mf < 4; ++mf)
#pragma unroll
    for (int nf = 0; nf < 3; ++nf)
#pragma unroll
      for (int rr = 0; rr < 4; ++rr) {
        int m = mf * 16 + ((lane >> 4) << 2) + rr;
        int n = w * 48 + nf * 16 + (lane & 15);
        pb[m * 192 + n] = acc[mf][nf][rr];
      }
}

// ---------- reduce partials, bias at DC bin, scores, softmax, ampT (f16, [d][j]) ----------
__global__ __launch_bounds__(256) void k_attn2(const float* __restrict__ part, const int* __restrict__ idxb,
                                               const float* __restrict__ bq, const float* __restrict__ bk,
                                               const float* __restrict__ bv, const float* __restrict__ Cre,
                                               f16* __restrict__ ampT) {
  __shared__ float sQKV[64][196];
  __shared__ float scores[64], attns[64];
  __shared__ int fjs[64];
  __shared__ int dcrow;
  int tid = threadIdx.x, bh = blockIdx.x;
  int b = bh >> 4, h = bh & 15;
  if (tid == 0) dcrow = -1;
  __syncthreads();
  if (tid < 64) {
    int f = idxb[bh * 64 + tid];
    fjs[tid] = f;
    if (f == 0) dcrow = tid;
  }
  __syncthreads();
  const float4* p0 = (const float4*)(part + (size_t)bh * 12288);
  const size_t s4 = (size_t)128 * 12288 / 4;
#pragma unroll
  for (int it = 0; it < 12; ++it) {
    int e = it * 256 + tid;
    float4 v0 = p0[e], v1 = p0[e + s4], v2 = p0[e + 2 * s4], v3 = p0[e + 3 * s4];
    float4 v;
    v.x = v0.x + v1.x + v2.x + v3.x;
    v.y = v0.y + v1.y + v2.y + v3.y;
    v.z = v0.z + v1.z + v2.z + v3.z;
    v.w = v0.w + v1.w + v2.w + v3.w;
    int m = e / 48, n0 = (e % 48) * 4;
    *(float4*)&sQKV[m][n0] = v;
  }
  __syncthreads();
  if (dcrow >= 0 && tid < 192) {
    const float* bias = (tid < 64) ? bq : (tid < 128) ? bk : bv;
    sQKV[dcrow][tid] += 4096.0f * bias[h * 64 + (tid & 63)];
  }
  __syncthreads();
  {
    int j = tid >> 2, p = tid & 3;
    float s = 0.f;
#pragma unroll
    for (int c = 0; c < 16; ++c) {
      int cc = p * 16 + c;
      s = fmaf(sQKV[j][cc], sQKV[j][64 + cc], s);
    }
    s += __shfl_xor(s, 1);
    s += __shfl_xor(s, 2);
    if (p == 0) scores[j] = s * 0.125f;
  }
  __syncthreads();
  if (tid < 64) {
    float s = scores[tid];
    float m = s;
#pragma unroll
    for (int off = 32; off > 0; off >>= 1) m = fmaxf(m, __shfl_xor(m, off));
    float ev = expf(s - m);
    float sm = ev;
#pragma unroll
    for (int off = 32; off > 0; off >>= 1) sm += __shfl_xor(sm, off);
    attns[tid] = ev / sm;
  }
  __syncthreads();
  {
    int j = tid >> 2, d0 = (tid & 3) * 16;
    float at = attns[j];
    int fj = fjs[j];
    float wj = (fj == 0 || fj == 2048) ? 0.5f : 1.0f;
#pragma unroll
    for (int q4 = 0; q4 < 4; ++q4) {
      float4 c4 = *(const float4*)&Cre[b * 1024 + h * 64 + d0 + q4 * 4];
      float4 vv = *(const float4*)&sQKV[j][128 + d0 + q4 * 4];
      float av0 = wj * (at * vv.x - c4.x);
      float av1 = wj * (at * vv.y - c4.y);
      float av2 = wj * (at * vv.z - c4.z);
      float av3 = wj * (at * vv.w - c4.w);
      f16* o = ampT + (size_t)bh * 4096 + (d0 + q4 * 4) * 64 + j;  // [bh][d][j]
      o[0] = (f16)av0; o[64] = (f16)av1; o[128] = (f16)av2; o[192] = (f16)av3;
    }
  }
}

// ---------- sparse irfft via MFMA: OT[t][d] = (2/L)(cosA[t][j]@ampT[j][d] + g(t)Cim[d]) + [t==0]Cre ----------
__global__ __launch_bounds__(256) void k_ot(const f16* __restrict__ ampT, const int* __restrict__ idxb,
                                            const float* __restrict__ Cre, const float* __restrict__ Cim,
                                            f16* __restrict__ OT) {
  __shared__ __align__(16) f16 sAmp[64][72];
  __shared__ float gbuf[256];
  __shared__ int fjs[64];
  int tid = threadIdx.x, lane = tid & 63, w = tid >> 6;
  int bh = blockIdx.x >> 4, tch = blockIdx.x & 15;
  int b = bh >> 4, h = bh & 15;
  if (tid < 64) fjs[tid] = idxb[bh * 64 + tid];
  {
    int row = tid >> 2, seg = tid & 3;
    const f16* src = ampT + (size_t)bh * 4096 + row * 64 + seg * 16;
    f16x8 v0 = *(const f16x8*)src;
    f16x8 v1 = *(const f16x8*)(src + 8);
    *(f16x8*)&sAmp[row][seg * 16] = v0;
    *(f16x8*)&sAmp[row][seg * 16 + 8] = v1;
  }
  __syncthreads();
  int r = lane & 15, q = lane >> 4;
  int tbase = tch * 256 + w * 64;
  const float cang = 0.00153398078788564123f;  // 2*pi/4096
  f16x8 aF[4][2];
  float ss[4];
#pragma unroll
  for (int mf = 0; mf < 4; ++mf) {
    int t = tbase + mf * 16 + r;
    float s = 0.f;
#pragma unroll
    for (int kk2 = 0; kk2 < 2; ++kk2) {
      f16x8 a;
#pragma unroll
      for (int jj = 0; jj < 8; ++jj) {
        int j = kk2 * 32 + q * 8 + jj;
        int ridx = (fjs[j] * t) & 4095;
        float sn, cs;
        __sincosf((float)ridx * cang, &sn, &cs);
        s += sn;
        a[jj] = (f16)cs;
      }
      aF[mf][kk2] = a;
    }
    ss[mf] = s;
  }
#pragma unroll
  for (int mf = 0; mf < 4; ++mf) {
    ss[mf] += __shfl_xor(ss[mf], 16);
    ss[mf] += __shfl_xor(ss[mf], 32);
  }
  if (q == 0) {
#pragma unroll
    for (int mf = 0; mf < 4; ++mf) {
      int t = tbase + mf * 16 + r;
      float g = ss[mf];
      if (t & 1) {
        int tp = (t <= 2048) ? t : 4096 - t;
        float sg = (t <= 2048) ? 1.f : -1.f;
        float aa = (float)tp * (PI_F / 4096.0f);
        g -= sg * (cosf(aa) / sinf(aa));
      }
      gbuf[w * 64 + mf * 16 + r] = g;
    }
  }
  f16x8 bF[4][2];
#pragma unroll
  for (int nf = 0; nf < 4; ++nf)
#pragma unroll
    for (int kk2 = 0; kk2 < 2; ++kk2)
      bF[nf][kk2] = *(const f16x8*)&sAmp[nf * 16 + r][kk2 * 32 + q * 8];
  f32x4 acc[4][4];
#pragma unroll
  for (int mf = 0; mf < 4; ++mf)
#pragma unroll
    for (int nf = 0; nf < 4; ++nf) acc[mf][nf] = 0;
#pragma unroll
  for (int kk2 = 0; kk2 < 2; ++kk2)
#pragma unroll
    for (int mf = 0; mf < 4; ++mf)
#pragma unroll
      for (int nf = 0; nf < 4; ++nf)
        acc[mf][nf] = __builtin_amdgcn_mfma_f32_16x16x32_f16(aF[mf][kk2], bF[nf][kk2], acc[mf][nf], 0, 0, 0);
  __syncthreads();
  const float s2L = 2.0f / 4096.0f;
#pragma unroll
  for (int nf = 0; nf < 4; ++nf) {
    int d = nf * 16 + r;
    float cim = Cim[b * 1024 + h * 64 + d];
    float cre = Cre[b * 1024 + h * 64 + d];
#pragma unroll
    for (int mf = 0; mf < 4; ++mf) {
#pragma unroll
      for (int rr = 0; rr < 4; ++rr) {
        int ro = mf * 16 + q * 4 + rr;
        int t = tbase + ro;
        float g = gbuf[w * 64 + ro];
        float val = s2L * (acc[mf][nf][rr] + cim * g) + ((t == 0) ? cre : 0.f);
        OT[((size_t)bh * 4096 + t) * 64 + d] = (f16)val;
      }
    }
  }
}

// ---------- final GEMM: out = OT @ Wo + bo; 128x256 block, waves 64x128, BK=32,
// paired-row swizzled LDS, depth-1 double buffer (measured-best) ----------
__global__ __launch_bounds__(256, 2) void k_final(const f16* __restrict__ OT, const f16* __restrict__ WoT,
                                                  const float* __restrict__ bo, float* __restrict__ out) {
  __shared__ __align__(16) char sM[2][24576];
  int tid = threadIdx.x, lane = tid & 63, w = tid >> 6;
  int lin = blockIdx.x;                 // 1024 = 128*8
  int sw = (lin & 7) * 128 + (lin >> 3);
  int bN = sw & 3, Mblk = sw >> 2;      // Mblk 0..255
  int wr = w >> 1, wc = w & 1;
  f32x4 acc[4][8];
#pragma unroll
  for (int mf = 0; mf < 4; ++mf)
#pragma unroll
    for (int nf = 0; nf < 8; ++nf) acc[mf][nf] = 0;
  int b = Mblk >> 5, t0 = (Mblk & 31) * 128;
  const char* gB0 = (const char*)WoT + (size_t)(bN * 256) * 2048;
  int r = lane & 15, q = lane >> 4;
  int aofs[4], bofs[8];
#pragma unroll
  for (int mf = 0; mf < 4; ++mf) aofs[mf] = pofs(wr * 64 + mf * 16 + r, q);
#pragma unroll
  for (int nf = 0; nf < 8; ++nf) bofs[nf] = 8192 + pofs(wc * 128 + nf * 16 + r, q);
  // A K-step ks: head = ks>>1, 64B half (ks&1) of that head's 128B t-row
#define GA_HEAD(ks) ((const char*)OT + ((size_t)(b * 16 + ((ks) >> 1)) * 4096 + t0) * 128)

  char* b0 = &sM[0][0];
  char* b1 = &sM[1][0];
  auto compute = [&](const char* base) {
    f16x8 aF[4], bF[8];
#pragma unroll
    for (int mf = 0; mf < 4; ++mf) aF[mf] = *(const f16x8*)(base + aofs[mf]);
#pragma unroll
    for (int nf = 0; nf < 8; ++nf) bF[nf] = *(const f16x8*)(base + bofs[nf]);
#pragma unroll
    for (int mf = 0; mf < 4; ++mf)
#pragma unroll
      for (int nf = 0; nf < 8; ++nf)
        acc[mf][nf] = __builtin_amdgcn_mfma_f32_16x16x32_f16(aF[mf], bF[nf], acc[mf][nf], 0, 0, 0);
  };

  stgP<2>(GA_HEAD(0), 128, 0, b0, tid, w);
  stgP<4>(gB0, 2048, 0, b0 + 8192, tid, w);
  for (int t = 0; t < 16; ++t) {
    int ks1 = 2 * t + 1;
    stgP<2>(GA_HEAD(ks1), 128, (ks1 & 1) * 64, b1, tid, w);
    stgP<4>(gB0, 2048, ks1 * 64, b1 + 8192, tid, w);
    asm volatile("s_waitcnt vmcnt(6)\ns_barrier" ::: "memory");
    compute(b0);
    asm volatile("s_barrier" ::: "memory");
    if (t < 15) {
      int ks0 = 2 * t + 2;
      stgP<2>(GA_HEAD(ks0), 128, (ks0 & 1) * 64, b0, tid, w);
      stgP<4>(gB0, 2048, ks0 * 64, b0 + 8192, tid, w);
      asm volatile("s_waitcnt vmcnt(6)\ns_barrier" ::: "memory");
    } else {
      asm volatile("s_waitcnt vmcnt(0)\ns_barrier" ::: "memory");
    }
    compute(b1);
    asm volatile("s_barrier" ::: "memory");
  }
#undef GA_HEAD
#pragma unroll
  for (int nf = 0; nf < 8; ++nf) {
    int gcol = bN * 256 + wc * 128 + nf * 16 + r;
    float bcol = bo[gcol];
#pragma unroll
    for (int mf = 0; mf < 4; ++mf) {
#pragma unroll
      for (int rr = 0; rr < 4; ++rr) {
        int grow = Mblk * 128 + wr * 64 + mf * 16 + (q << 2) + rr;
        out[(size_t)grow * 1024 + gcol] = acc[mf][nf][rr] + bcol;
      }
    }
  }
}

extern "C" void kernel_launch(void* const* d_in, const int* in_sizes, int n_in,
                              void* d_out, int out_size, void* d_ws, size_t ws_size,
                              hipStream_t stream) {
  const float* X = (const float*)d_in[0];
  const float* Wq = (const float*)d_in[1];
  const float* bq = (const float*)d_in[2];
  const float* Wk = (const float*)d_in[3];
  const float* bk = (const float*)d_in[4];
  const float* Wv = (const float*)d_in[5];
  const float* bv = (const float*)d_in[6];
  const float* Wo = (const float*)d_in[7];
  const float* bo = (const float*)d_in[8];
  float* out = (float*)d_out;

  if (ws_size < 208928768ULL) return;
  char* w = (char*)d_ws;
  // Region1 (0..134MB): Xt16 f16 (B,D,L) 67MB; after FFT reused for PT (71MB);
  // [71.3M) WkT WvT part (written after k_fft only)
  f16* Xt16 = (f16*)(w);
  f16* PT = (f16*)(w);
  f16* WkT = (f16*)(w + 71303168);
  f16* WvT = (f16*)(w + 73400320);
  float* part = (float*)(w + 75497472);
  char* R2 = w + 134217728;
  f16* PReU = (f16*)(R2);
  f16* PImU = (f16*)(R2 + 33570816);
  f16* OT = (f16*)(R2);
  char* R3 = R2 + 67141632;
  float* sumXf = (float*)(R3);
  float* Cre = (float*)(R3 + 65536);
  float* Cim = (float*)(R3 + 98304);
  float* energy = (float*)(R3 + 131072);
  int* idxb = (int*)(R3 + 1245184);
  f16* ampT = (f16*)(R3 + 1277952);
  f16* WqT = (f16*)(R3 + 3375104);
  f16* WoT = (f16*)(R3 + 5472256);
  // FFT tables live in d_out's head: dead until k_final overwrites all of d_out.
  float2* twtab = (float2*)d_out;
  float2* utab = twtab + 2048;

  dim3 b32(32, 8);
  hipLaunchKernelGGL(k_tw, dim3(17), dim3(256), 0, stream, twtab, utab);
  hipLaunchKernelGGL(k_prep, dim3(32, 32, 2), b32, 0, stream, Wq, Wo, WqT, WoT);
  hipLaunchKernelGGL(k_t1, dim3(64, 16, 8), dim3(256), 0, stream, X, Xt16);
  hipLaunchKernelGGL(k_fft, dim3(8192), dim3(256), 0, stream, Xt16, twtab, utab, PReU, PImU, sumXf);
  hipLaunchKernelGGL(k_prep2, dim3(32, 32, 2), b32, 0, stream, Wk, Wv, WkT, WvT);
  hipLaunchKernelGGL(k_C, dim3(32), dim3(256), 0, stream, sumXf, Wq, bq, Cre, Cim);
  hipLaunchKernelGGL(k_t2, dim3(68, 16, 16), dim3(256), 0, stream, PReU, PImU, PT);
  hipLaunchKernelGGL(k_energy, dim3(1088), dim3(256), 0, stream, PT, WqT, bq, energy);
  hipLaunchKernelGGL(k_topk, dim3(128), dim3(256), 0, stream, energy, idxb);
  hipLaunchKernelGGL(k_qkv, dim3(128, 4), dim3(256), 0, stream, PT, idxb, WqT, WkT, WvT, part);
  hipLaunchKernelGGL(k_attn2, dim3(128), dim3(256), 0, stream, part, idxb, bq, bk, bv, Cre, ampT);
  hipLaunchKernelGGL(k_ot, dim3(2048), dim3(256), 0, stream, ampT, idxb, Cre, Cim, OT);
  hipLaunchKernelGGL(k_final, dim3(1024), dim3(256), 0, stream, OT, WoT, bo, out);
}